// Round 7
// baseline (527.076 us; speedup 1.0000x reference)
//
#include <hip/hip_runtime.h>
#include <hip/hip_bf16.h>

// ---------------- problem dims ----------------
#define NT  512      // tokens
#define NH  2048     // hidden
#define NE  8        // experts
#define NI  1408     // expert intermediate
#define NIS 5632     // shared intermediate

typedef __bf16 bf16x8 __attribute__((ext_vector_type(8)));
typedef float  f32x4  __attribute__((ext_vector_type(4)));

// async global->LDS DMA, 16B per lane, wave-uniform LDS base + lane*16
#define GLDS(gp, lp) __builtin_amdgcn_global_load_lds( \
    (const __attribute__((address_space(1))) void*)(gp), \
    (__attribute__((address_space(3))) void*)(lp), 16, 0, 0)

// ---------------- workspace layout (bytes) ----------------
static constexpr size_t WS_XBF  = 0;                                  // 512*2048 bf16
static constexpr size_t WS_SEL  = WS_XBF + (size_t)NT*NH*2;           // 1024 int
static constexpr size_t WS_WTS  = WS_SEL + 4096;
static constexpr size_t WS_CNT  = WS_WTS + 4096;
static constexpr size_t WS_OFFE = WS_CNT + 32;
static constexpr size_t WS_TOK  = WS_OFFE + 32;
static constexpr size_t WS_PWT  = WS_TOK + 4096;
static constexpr size_t WS_SLOT = WS_PWT + 4096;
static constexpr size_t WS_G    = WS_SLOT + 4096;                     // 1024*1408 bf16
static constexpr size_t WS_U    = WS_G   + (size_t)1024*NI*2;
static constexpr size_t WS_HBF  = WS_U   + (size_t)1024*NI*2;         // 1024*1408 bf16
static constexpr size_t WS_PAIR = WS_HBF + (size_t)1024*NI*2;         // 1024*2048 bf16
static constexpr size_t WS_SHG  = WS_PAIR+ (size_t)1024*NH*2;         // 512*5632 bf16
static constexpr size_t WS_SHU  = WS_SHG + (size_t)NT*NIS*2;
static constexpr size_t WS_SHBF = WS_SHU + (size_t)NT*NIS*2;
static constexpr size_t WS_SHP  = WS_SHBF+ (size_t)NT*NIS*2;          // 4*512*2048 bf16
static constexpr size_t WS_WE   = WS_SHP + (size_t)4*NT*NH*2;         // 8*2048*1408 bf16 (reused 3x)
static constexpr size_t WS_WS2  = WS_WE  + (size_t)NE*NH*NI*2;        // 5632*2048 bf16 (reused 3x)

// ---------------- router ----------------
__global__ void router_kernel(const float* __restrict__ x, const float* __restrict__ gw,
                              float* __restrict__ out_logits,
                              int* __restrict__ sel, float* __restrict__ wts)
{
    int tid = threadIdx.x;
    int t = blockIdx.x * 32 + (tid >> 3);
    int e = tid & 7;
    const float* xr = x + (size_t)t * NH;
    const float* gr = gw + (size_t)e * NH;
    float acc = 0.f;
    for (int k = 0; k < NH; k += 4) {
        float4 xv = *(const float4*)(xr + k);
        float4 gv = *(const float4*)(gr + k);
        acc += xv.x*gv.x + xv.y*gv.y + xv.z*gv.z + xv.w*gv.w;
    }
    out_logits[(size_t)t * NE + e] = acc;

    __shared__ float lg[32][8];
    lg[tid >> 3][e] = acc;
    __syncthreads();
    if (e == 0) {
        int ti = tid >> 3;
        float l[8];
        #pragma unroll
        for (int j = 0; j < 8; ++j) l[j] = lg[ti][j];
        int i1 = 0;
        #pragma unroll
        for (int j = 1; j < 8; ++j) if (l[j] > l[i1]) i1 = j;
        int i2 = -1;
        #pragma unroll
        for (int j = 0; j < 8; ++j) {
            if (j == i1) continue;
            if (i2 < 0 || l[j] > l[i2]) i2 = j;
        }
        float d  = expf(l[i2] - l[i1]);
        float w1 = 1.f / (1.f + d);
        float w2 = 1.f - w1;
        sel[2*t]   = i1;  sel[2*t+1] = i2;
        wts[2*t]   = w1;  wts[2*t+1] = w2;
    }
}

// ---------------- deterministic bucketing ----------------
__global__ void bucket_kernel(const int* __restrict__ sel, const float* __restrict__ wts,
                              int* __restrict__ cnt, int* __restrict__ offe,
                              int* __restrict__ tok, float* __restrict__ pwt,
                              int* __restrict__ slot)
{
    int e = threadIdx.x;
    __shared__ int scnt[8];
    __shared__ int soff[8];
    if (e < 8) {
        int c = 0;
        for (int t = 0; t < NT; ++t) {
            if (sel[2*t]   == e) c++;
            if (sel[2*t+1] == e) c++;
        }
        scnt[e] = c;
        cnt[e] = c;
    }
    __syncthreads();
    if (threadIdx.x == 0) {
        int s = 0;
        for (int j = 0; j < 8; ++j) { soff[j] = s; offe[j] = s; s += scnt[j]; }
    }
    __syncthreads();
    if (e < 8) {
        int p = soff[e];
        for (int t = 0; t < NT; ++t) {
            #pragma unroll
            for (int k = 0; k < 2; ++k) {
                if (sel[2*t+k] == e) {
                    tok[p] = t;
                    pwt[p] = wts[2*t+k];
                    slot[2*t+k] = p;
                    p++;
                }
            }
        }
    }
}

// ---------------- fp32 -> bf16 cast (activations) ----------------
__global__ void cast_kernel(const float* __restrict__ src, __bf16* __restrict__ dst, long long n)
{
    long long i = ((long long)blockIdx.x * blockDim.x + threadIdx.x) * 4;
    if (i >= n) return;
    float4 v = *(const float4*)(src + i);
    __bf16 o[4] = { (__bf16)v.x, (__bf16)v.y, (__bf16)v.z, (__bf16)v.w };
    *(uint2*)(dst + i) = *(const uint2*)o;
}

// ---------------- weight convert+transpose: f32 [K][N] -> bf16 [N][K] -------
// z < nzA: tensor-A batch z; else tensor-B (single). 64x64 tiles, 256 thr.
__global__ void conv_kernel(const float* __restrict__ srcA, __bf16* __restrict__ dstA,
                            int KA, int NA, int nzA, size_t sstrA,
                            const float* __restrict__ srcB, __bf16* __restrict__ dstB,
                            int KB, int NB)
{
    int z = blockIdx.z;
    const float* src; __bf16* dst; int K, N;
    if (z < nzA) { src = srcA + sstrA * z; dst = dstA + sstrA * z; K = KA; N = NA; }
    else         { src = srcB;             dst = dstB;             K = KB; N = NB; }
    int nt = blockIdx.x, kt = blockIdx.y;
    if (nt * 64 >= N || kt * 64 >= K) return;

    __shared__ float ls[64][65];
    int tid = threadIdx.x;
    int n4 = tid & 15, kr = tid >> 4;
    #pragma unroll
    for (int p = 0; p < 4; ++p) {
        int k = p * 16 + kr;
        float4 v = *(const float4*)(src + (size_t)(kt*64 + k) * N + nt*64 + n4*4);
        ls[k][n4*4+0] = v.x; ls[k][n4*4+1] = v.y; ls[k][n4*4+2] = v.z; ls[k][n4*4+3] = v.w;
    }
    __syncthreads();
    int nl = tid >> 2, kq = tid & 3;
    __bf16 o[16];
    #pragma unroll
    for (int i = 0; i < 16; ++i) o[i] = (__bf16)ls[kq*16 + i][nl];
    __bf16* dp = dst + (size_t)(nt*64 + nl) * K + kt*64 + kq*16;
    *(uint4*)(dp)     = ((const uint4*)o)[0];
    *(uint4*)(dp + 8) = ((const uint4*)o)[1];
}

// ---------------- fused silu(g)*u (bf16 in/out) ----------------
__global__ void silu_fused_kernel(const __bf16* __restrict__ g1, const __bf16* __restrict__ u1,
                                  __bf16* __restrict__ h1, long long n1,
                                  const __bf16* __restrict__ g2, const __bf16* __restrict__ u2,
                                  __bf16* __restrict__ h2, long long n2)
{
    long long i = ((long long)blockIdx.x * blockDim.x + threadIdx.x) * 8;
    const __bf16 *g, *u; __bf16* h; long long idx;
    if (i < n1)           { g = g1; u = u1; h = h1; idx = i; }
    else if (i < n1 + n2) { g = g2; u = u2; h = h2; idx = i - n1; }
    else return;
    uint4 gv = *(const uint4*)(g + idx);
    uint4 uv = *(const uint4*)(u + idx);
    const __bf16* gp = (const __bf16*)&gv;
    const __bf16* up = (const __bf16*)&uv;
    __bf16 o[8];
    #pragma unroll
    for (int j = 0; j < 8; ++j) {
        float x = (float)gp[j];
        float y = x / (1.f + __expf(-x)) * (float)up[j];
        o[j] = (__bf16)y;
    }
    *(uint4*)(h + idx) = *(const uint4*)o;
}

// ============ core 128x128 MFMA GEMM (m97 structure, global_load_lds) ======
// C[base+r, n0..] = sum_k A[row(r), k] * BT[n, k], all bf16, K-contiguous.
// NK = K/32 steps. LDS: As[2][128][32] + Bs[2][128][32] bf16 = 32KB; smem 36KB.
template<int NK, bool GATHER>
__device__ __forceinline__ void gemm_core(char* __restrict__ smem,
    const __bf16* __restrict__ A, int lda,
    const __bf16* __restrict__ BT, int ldb,
    __bf16* __restrict__ C, int ldc,
    int rows, int base, const int* __restrict__ tok, int m0, int n0)
{
    const int tid  = threadIdx.x;
    const int lane = tid & 63;
    const int wid  = tid >> 6;           // 4 waves, 2x2 grid of 64x64
    const int wr   = wid >> 1, wc = wid & 1;

    // ---- staging map: wave instr s (2 per operand) covers rows [(wid*2+s)*16, +16)
    // lane l -> row (l>>2), chunk (l&3); source chunk XOR-swizzled: cs = c ^ (r&3)
    const int rs0 = (wid*2 + 0)*16 + (lane >> 2);
    const int rs1 = (wid*2 + 1)*16 + (lane >> 2);
    const int cch = lane & 3;
    int ga0 = m0 + rs0, ga1 = m0 + rs1;
    int ar0, ar1;
    if (GATHER) {
        ar0 = tok[base + (ga0 < rows ? ga0 : 0)];
        ar1 = tok[base + (ga1 < rows ? ga1 : 0)];
    } else {
        ar0 = base + (ga0 < rows ? ga0 : 0);
        ar1 = base + (ga1 < rows ? ga1 : 0);
    }
    const __bf16* a0p = A  + (size_t)ar0 * lda + (cch ^ (rs0 & 3)) * 8;
    const __bf16* a1p = A  + (size_t)ar1 * lda + (cch ^ (rs1 & 3)) * 8;
    const __bf16* b0p = BT + (size_t)(n0 + rs0) * ldb + (cch ^ (rs0 & 3)) * 8;
    const __bf16* b1p = BT + (size_t)(n0 + rs1) * ldb + (cch ^ (rs1 & 3)) * 8;
    char* lA0 = smem + (wid*2 + 0) * 1024;   // 16 rows * 64B
    char* lA1 = smem + (wid*2 + 1) * 1024;

#define STAGE(b, t)                                             \
    {                                                           \
        GLDS(a0p + (t)*32, lA0 + (b)*8192);                     \
        GLDS(a1p + (t)*32, lA1 + (b)*8192);                     \
        GLDS(b0p + (t)*32, lA0 + 16384 + (b)*8192);             \
        GLDS(b1p + (t)*32, lA1 + 16384 + (b)*8192);             \
    }

    // ---- fragment read offsets (bytes), same XOR on read side
    const int fr = lane & 15, fq = lane >> 4;
    const int aoff = ((wr*64 + fr)*32 + ((fq ^ (fr & 3)) * 8)) * 2;
    const int boff = ((wc*64 + fr)*32 + ((fq ^ (fr & 3)) * 8)) * 2;

    f32x4 acc[4][4];
    #pragma unroll
    for (int i = 0; i < 4; ++i)
        #pragma unroll
        for (int j = 0; j < 4; ++j) acc[i][j] = f32x4{0.f,0.f,0.f,0.f};

    STAGE(0, 0);
    asm volatile("s_waitcnt vmcnt(0)" ::: "memory");
    __builtin_amdgcn_s_barrier();

    #pragma unroll 1
    for (int t = 0; t < NK; ++t) {
        int nt = (t + 1 < NK) ? t + 1 : NK - 1;      // clamped (harmless re-stage)
        STAGE((t + 1) & 1, nt);                       // async into other buffer
        asm volatile("s_waitcnt vmcnt(4)" ::: "memory");  // tile t's 4 DMAs done
        __builtin_amdgcn_s_barrier();

        const char* Ab = smem + (t & 1) * 8192;
        const char* Bb = smem + 16384 + (t & 1) * 8192;
        bf16x8 af[4], bfr[4];
        #pragma unroll
        for (int m = 0; m < 4; ++m) af[m]  = *(const bf16x8*)(Ab + aoff + m*1024);
        #pragma unroll
        for (int n = 0; n < 4; ++n) bfr[n] = *(const bf16x8*)(Bb + boff + n*1024);
        __builtin_amdgcn_s_setprio(1);
        #pragma unroll
        for (int m = 0; m < 4; ++m)
            #pragma unroll
            for (int n = 0; n < 4; ++n)
                acc[m][n] = __builtin_amdgcn_mfma_f32_16x16x32_bf16(af[m], bfr[n], acc[m][n], 0, 0, 0);
        __builtin_amdgcn_s_setprio(0);
        asm volatile("s_waitcnt lgkmcnt(0)" ::: "memory");  // reads of buf done
        __builtin_amdgcn_s_barrier();
    }
#undef STAGE

    // ---- epilogue: per-wave LDS transpose (bf16), coalesced 16B row stores
    asm volatile("s_waitcnt vmcnt(0) lgkmcnt(0)" ::: "memory");  // drain stray DMA
    __builtin_amdgcn_s_barrier();

    __bf16* ep = (__bf16*)(smem + wid * 9216);   // 64 rows x 72 bf16 (144B, 16B-aligned)
    #pragma unroll
    for (int m = 0; m < 4; ++m)
        #pragma unroll
        for (int n = 0; n < 4; ++n)
            #pragma unroll
            for (int q = 0; q < 4; ++q)
                ep[(m*16 + fq*4 + q)*72 + n*16 + fr] = (__bf16)acc[m][n][q];

    const int grow = m0 + wr*64 + lane;
    if (grow < rows) {
        __bf16* cp = C + (size_t)(base + grow) * ldc + n0 + wc*64;
        const __bf16* rp = ep + lane * 72;
        #pragma unroll
        for (int j = 0; j < 8; ++j)
            *(uint4*)(cp + j*8) = *(const uint4*)(rp + j*8);
    }
}

// ---------------- phase 1/2 wrapper: expert (z<8) + shared (z=8) -----------
__launch_bounds__(256, 4)
__global__ void gemm_p1(const __bf16* __restrict__ xbf,
                        const __bf16* __restrict__ WeT, const __bf16* __restrict__ WsT,
                        __bf16* __restrict__ Ce, __bf16* __restrict__ Cs,
                        const int* __restrict__ cnt, const int* __restrict__ offe,
                        const int* __restrict__ tok)
{
    __shared__ alignas(16) char smem[36864];
    int z = blockIdx.z;
    if (z < 8) {
        if (blockIdx.x >= NI/128) return;       // 11 n-tiles
        int rows = cnt[z], base = offe[z];
        int m0 = blockIdx.y * 128; if (m0 >= rows) return;
        gemm_core<NH/32, true>(smem, xbf, NH, WeT + (size_t)z * NH * NI, NH,
                               Ce, NI, rows, base, tok, m0, blockIdx.x * 128);
    } else {
        gemm_core<NH/32, false>(smem, xbf, NH, WsT, NH,
                                Cs, NIS, NT, 0, nullptr, blockIdx.y * 128, blockIdx.x * 128);
    }
}

// ---------------- phase 3 wrapper: expert down (z<8) + shared down splitK (z=8..11)
__launch_bounds__(256, 4)
__global__ void gemm_p3(const __bf16* __restrict__ hbf, const __bf16* __restrict__ shbf,
                        const __bf16* __restrict__ WdT, const __bf16* __restrict__ WsdT,
                        __bf16* __restrict__ pair, __bf16* __restrict__ shp,
                        const int* __restrict__ cnt, const int* __restrict__ offe)
{
    __shared__ alignas(16) char smem[36864];
    int z = blockIdx.z;
    if (z < 8) {
        int rows = cnt[z], base = offe[z];
        int m0 = blockIdx.y * 128; if (m0 >= rows) return;
        gemm_core<NI/32, false>(smem, hbf, NI, WdT + (size_t)z * NH * NI, NI,
                                pair, NH, rows, base, nullptr, m0, blockIdx.x * 128);
    } else {
        int q = z - 8;                           // K-quarter
        gemm_core<NI/32, false>(smem, shbf + q * NI, NIS, WsdT + q * NI, NIS,
                                shp + (size_t)q * NT * NH, NH,
                                NT, 0, nullptr, blockIdx.y * 128, blockIdx.x * 128);
    }
}

// ---------------- final combine ----------------
__global__ void combine_kernel(const float* __restrict__ x, const float* __restrict__ shexp_w,
                               const __bf16* __restrict__ shp, const __bf16* __restrict__ pair_out,
                               const int* __restrict__ slot, const float* __restrict__ wts,
                               float* __restrict__ out)
{
    int t = blockIdx.x;
    int tid = threadIdx.x;
    const float* xr = x + (size_t)t * NH;

    float p = 0.f;
    #pragma unroll
    for (int j = 0; j < 8; ++j) {
        int k = tid * 8 + j;
        p += xr[k] * shexp_w[k];
    }
    __shared__ float red[256];
    red[tid] = p;
    __syncthreads();
    for (int s = 128; s > 0; s >>= 1) {
        if (tid < s) red[tid] += red[tid + s];
        __syncthreads();
    }
    float sig = 1.f / (1.f + expf(-red[0]));

    int   s0 = slot[2*t],   s1 = slot[2*t+1];
    float w0 = wts[2*t],    w1 = wts[2*t+1];
    const __bf16* pr0 = pair_out + (size_t)s0 * NH;
    const __bf16* pr1 = pair_out + (size_t)s1 * NH;
    const __bf16* sd  = shp + (size_t)t * NH;
    float* orow = out + (size_t)t * NH;
    const size_t PS = (size_t)NT * NH;
    for (int n = tid; n < NH; n += 256) {
        float sdv = (float)sd[n] + (float)sd[n + PS] + (float)sd[n + 2*PS] + (float)sd[n + 3*PS];
        orow[n] = sdv * sig + w0 * (float)pr0[n] + w1 * (float)pr1[n];
    }
}

// ---------------- launch ----------------
extern "C" void kernel_launch(void* const* d_in, const int* in_sizes, int n_in,
                              void* d_out, int out_size, void* d_ws, size_t ws_size,
                              hipStream_t stream)
{
    const float* x       = (const float*)d_in[0];
    const float* gate_w  = (const float*)d_in[1];
    const float* w_gate  = (const float*)d_in[2];
    const float* w_up    = (const float*)d_in[3];
    const float* w_down  = (const float*)d_in[4];
    const float* sh_gate = (const float*)d_in[5];
    const float* sh_up   = (const float*)d_in[6];
    const float* sh_down = (const float*)d_in[7];
    const float* shexp_g = (const float*)d_in[8];

    float* out        = (float*)d_out;
    float* out_logits = out + (size_t)NT * NH;

    char* ws = (char*)d_ws;
    __bf16* xbf  = (__bf16*)(ws + WS_XBF);
    int*    sel  = (int*)  (ws + WS_SEL);
    float*  wts  = (float*)(ws + WS_WTS);
    int*    cnt  = (int*)  (ws + WS_CNT);
    int*    offe = (int*)  (ws + WS_OFFE);
    int*    tok  = (int*)  (ws + WS_TOK);
    float*  pwt  = (float*)(ws + WS_PWT);
    int*    slot = (int*)  (ws + WS_SLOT);
    __bf16* gbuf = (__bf16*)(ws + WS_G);
    __bf16* ubuf = (__bf16*)(ws + WS_U);
    __bf16* hbf  = (__bf16*)(ws + WS_HBF);
    __bf16* pair = (__bf16*)(ws + WS_PAIR);
    __bf16* shg  = (__bf16*)(ws + WS_SHG);
    __bf16* shu  = (__bf16*)(ws + WS_SHU);
    __bf16* shbf = (__bf16*)(ws + WS_SHBF);
    __bf16* shp  = (__bf16*)(ws + WS_SHP);
    __bf16* WeT  = (__bf16*)(ws + WS_WE);    // expert weight^T region (reused 3x)
    __bf16* WsT  = (__bf16*)(ws + WS_WS2);   // shared weight^T region (reused 3x)
    (void)pwt; (void)in_sizes; (void)n_in; (void)out_size; (void)ws_size;

    router_kernel<<<dim3(16), dim3(256), 0, stream>>>(x, gate_w, out_logits, sel, wts);
    bucket_kernel<<<dim3(1), dim3(64), 0, stream>>>(sel, wts, cnt, offe, tok, pwt, slot);
    cast_kernel<<<dim3(1024), dim3(256), 0, stream>>>(x, xbf, (long long)NT * NH);

    // ---- gate round: convert w_gate (8x [2048][1408]) + sh_gate ([2048][5632])
    conv_kernel<<<dim3(88, 32, 9), dim3(256), 0, stream>>>(
        w_gate, WeT, NH, NI, 8, (size_t)NH * NI, sh_gate, WsT, NH, NIS);
    gemm_p1<<<dim3(44, 4, 9), dim3(256), 0, stream>>>(
        xbf, WeT, WsT, gbuf, shg, cnt, offe, tok);

    // ---- up round
    conv_kernel<<<dim3(88, 32, 9), dim3(256), 0, stream>>>(
        w_up, WeT, NH, NI, 8, (size_t)NH * NI, sh_up, WsT, NH, NIS);
    gemm_p1<<<dim3(44, 4, 9), dim3(256), 0, stream>>>(
        xbf, WeT, WsT, ubuf, shu, cnt, offe, tok);

    // ---- silu
    silu_fused_kernel<<<dim3(2112), dim3(256), 0, stream>>>(
        gbuf, ubuf, hbf, (long long)1024 * NI,
        shg, shu, shbf, (long long)NT * NIS);

    // ---- down round: w_down (8x [1408][2048]) + sh_down ([5632][2048])
    conv_kernel<<<dim3(32, 88, 9), dim3(256), 0, stream>>>(
        w_down, WeT, NI, NH, 8, (size_t)NI * NH, sh_down, WsT, NIS, NH);
    gemm_p3<<<dim3(16, 4, 12), dim3(256), 0, stream>>>(
        hbf, shbf, WeT, WsT, pair, shp, cnt, offe);

    combine_kernel<<<dim3(NT), dim3(256), 0, stream>>>(
        x, shexp_g, shp, pair, slot, wts, out);
}

// Round 8
// 399.623 us; speedup vs baseline: 1.3189x; 1.3189x over previous
//
#include <hip/hip_runtime.h>
#include <hip/hip_bf16.h>

// ---------------- problem dims ----------------
#define NT  512      // tokens
#define NH  2048     // hidden
#define NE  8        // experts
#define NI  1408     // expert intermediate
#define NIS 5632     // shared intermediate

typedef __bf16 bf16x8 __attribute__((ext_vector_type(8)));
typedef float  f32x4  __attribute__((ext_vector_type(4)));

// async global->LDS DMA, 16B per lane, wave-uniform LDS base + lane*16
#define GLDS(gp, lp) __builtin_amdgcn_global_load_lds( \
    (const __attribute__((address_space(1))) void*)(gp), \
    (__attribute__((address_space(3))) void*)(lp), 16, 0, 0)

// ---------------- workspace layout (bytes) ----------------
static constexpr size_t WS_XBF  = 0;                                  // 512*2048 bf16
static constexpr size_t WS_SEL  = WS_XBF + (size_t)NT*NH*2;           // 1024 int
static constexpr size_t WS_WTS  = WS_SEL + 4096;
static constexpr size_t WS_CNT  = WS_WTS + 4096;
static constexpr size_t WS_OFFE = WS_CNT + 32;
static constexpr size_t WS_TOK  = WS_OFFE + 32;
static constexpr size_t WS_PWT  = WS_TOK + 4096;
static constexpr size_t WS_SLOT = WS_PWT + 4096;
static constexpr size_t WS_G    = WS_SLOT + 4096;                     // 1024*1408 bf16
static constexpr size_t WS_U    = WS_G   + (size_t)1024*NI*2;
static constexpr size_t WS_HBF  = WS_U   + (size_t)1024*NI*2;         // 1024*1408 bf16
static constexpr size_t WS_PAIR = WS_HBF + (size_t)1024*NI*2;         // 1024*2048 bf16
static constexpr size_t WS_SHG  = WS_PAIR+ (size_t)1024*NH*2;         // 512*5632 bf16
static constexpr size_t WS_SHU  = WS_SHG + (size_t)NT*NIS*2;
static constexpr size_t WS_SHBF = WS_SHU + (size_t)NT*NIS*2;
static constexpr size_t WS_SHP  = WS_SHBF+ (size_t)NT*NIS*2;          // 4*512*2048 bf16
static constexpr size_t WS_WE   = WS_SHP + (size_t)4*NT*NH*2;         // 8*2048*1408 bf16 (reused 3x)
static constexpr size_t WS_WS2  = WS_WE  + (size_t)NE*NH*NI*2;        // 5632*2048 bf16 (reused 3x)

// ---------------- router ----------------
__global__ void router_kernel(const float* __restrict__ x, const float* __restrict__ gw,
                              float* __restrict__ out_logits,
                              int* __restrict__ sel, float* __restrict__ wts)
{
    int tid = threadIdx.x;
    int t = blockIdx.x * 32 + (tid >> 3);
    int e = tid & 7;
    const float* xr = x + (size_t)t * NH;
    const float* gr = gw + (size_t)e * NH;
    float acc = 0.f;
    for (int k = 0; k < NH; k += 4) {
        float4 xv = *(const float4*)(xr + k);
        float4 gv = *(const float4*)(gr + k);
        acc += xv.x*gv.x + xv.y*gv.y + xv.z*gv.z + xv.w*gv.w;
    }
    out_logits[(size_t)t * NE + e] = acc;

    __shared__ float lg[32][8];
    lg[tid >> 3][e] = acc;
    __syncthreads();
    if (e == 0) {
        int ti = tid >> 3;
        float l[8];
        #pragma unroll
        for (int j = 0; j < 8; ++j) l[j] = lg[ti][j];
        int i1 = 0;
        #pragma unroll
        for (int j = 1; j < 8; ++j) if (l[j] > l[i1]) i1 = j;
        int i2 = -1;
        #pragma unroll
        for (int j = 0; j < 8; ++j) {
            if (j == i1) continue;
            if (i2 < 0 || l[j] > l[i2]) i2 = j;
        }
        float d  = expf(l[i2] - l[i1]);
        float w1 = 1.f / (1.f + d);
        float w2 = 1.f - w1;
        sel[2*t]   = i1;  sel[2*t+1] = i2;
        wts[2*t]   = w1;  wts[2*t+1] = w2;
    }
}

// ---------------- wave-parallel deterministic bucketing ----------------
// 8 waves; wave e owns expert e. Entry idx = 2*t+k, scanned in idx order via
// 16 ballot chunks of 64 -> same compact order as a serial scan.
__global__ void bucket_kernel(const int* __restrict__ sel, const float* __restrict__ wts,
                              int* __restrict__ cnt, int* __restrict__ offe,
                              int* __restrict__ tok, float* __restrict__ pwt,
                              int* __restrict__ slot)
{
    int tid  = threadIdx.x;          // 0..511
    int wid  = tid >> 6;             // expert id
    int lane = tid & 63;
    __shared__ int scnt[8], soff[8];

    unsigned long long masks[16];
    int total = 0;
    #pragma unroll
    for (int c = 0; c < 16; ++c) {
        int idx = c * 64 + lane;
        int s = sel[idx];
        unsigned long long m = __ballot(s == wid);
        masks[c] = m;
        total += __popcll(m);
    }
    if (lane == 0) { scnt[wid] = total; cnt[wid] = total; }
    __syncthreads();
    if (tid == 0) {
        int s = 0;
        #pragma unroll
        for (int j = 0; j < 8; ++j) { soff[j] = s; offe[j] = s; s += scnt[j]; }
    }
    __syncthreads();
    int pfx = soff[wid];
    unsigned long long below = (lane == 63) ? ~0ull >> 1 : ((1ull << lane) - 1);
    #pragma unroll
    for (int c = 0; c < 16; ++c) {
        int idx = c * 64 + lane;
        unsigned long long m = masks[c];
        if ((m >> lane) & 1ull) {
            int rank = pfx + (int)__popcll(m & below);
            tok[rank]  = idx >> 1;
            pwt[rank]  = wts[idx];
            slot[idx]  = rank;
        }
        pfx += (int)__popcll(m);
    }
}

// ---------------- fp32 -> bf16 cast (activations) ----------------
__global__ void cast_kernel(const float* __restrict__ src, __bf16* __restrict__ dst, long long n)
{
    long long i = ((long long)blockIdx.x * blockDim.x + threadIdx.x) * 4;
    if (i >= n) return;
    float4 v = *(const float4*)(src + i);
    __bf16 o[4] = { (__bf16)v.x, (__bf16)v.y, (__bf16)v.z, (__bf16)v.w };
    *(uint2*)(dst + i) = *(const uint2*)o;
}

// ---------------- weight convert+transpose: f32 [K][N] -> bf16 [N][K] -------
// z < nzA: tensor-A batch z; else tensor-B (single). 64x64 tiles, 256 thr.
__global__ void conv_kernel(const float* __restrict__ srcA, __bf16* __restrict__ dstA,
                            int KA, int NA, int nzA, size_t sstrA,
                            const float* __restrict__ srcB, __bf16* __restrict__ dstB,
                            int KB, int NB)
{
    int z = blockIdx.z;
    const float* src; __bf16* dst; int K, N;
    if (z < nzA) { src = srcA + sstrA * z; dst = dstA + sstrA * z; K = KA; N = NA; }
    else         { src = srcB;             dst = dstB;             K = KB; N = NB; }
    int nt = blockIdx.x, kt = blockIdx.y;
    if (nt * 64 >= N || kt * 64 >= K) return;

    __shared__ float ls[64][65];
    int tid = threadIdx.x;
    int n4 = tid & 15, kr = tid >> 4;
    #pragma unroll
    for (int p = 0; p < 4; ++p) {
        int k = p * 16 + kr;
        float4 v = *(const float4*)(src + (size_t)(kt*64 + k) * N + nt*64 + n4*4);
        ls[k][n4*4+0] = v.x; ls[k][n4*4+1] = v.y; ls[k][n4*4+2] = v.z; ls[k][n4*4+3] = v.w;
    }
    __syncthreads();
    int nl = tid >> 2, kq = tid & 3;
    __bf16 o[16];
    #pragma unroll
    for (int i = 0; i < 16; ++i) o[i] = (__bf16)ls[kq*16 + i][nl];
    __bf16* dp = dst + (size_t)(nt*64 + nl) * K + kt*64 + kq*16;
    *(uint4*)(dp)     = ((const uint4*)o)[0];
    *(uint4*)(dp + 8) = ((const uint4*)o)[1];
}

// ---------------- fused silu(g)*u (bf16 in/out) ----------------
__global__ void silu_fused_kernel(const __bf16* __restrict__ g1, const __bf16* __restrict__ u1,
                                  __bf16* __restrict__ h1, long long n1,
                                  const __bf16* __restrict__ g2, const __bf16* __restrict__ u2,
                                  __bf16* __restrict__ h2, long long n2)
{
    long long i = ((long long)blockIdx.x * blockDim.x + threadIdx.x) * 8;
    const __bf16 *g, *u; __bf16* h; long long idx;
    if (i < n1)           { g = g1; u = u1; h = h1; idx = i; }
    else if (i < n1 + n2) { g = g2; u = u2; h = h2; idx = i - n1; }
    else return;
    uint4 gv = *(const uint4*)(g + idx);
    uint4 uv = *(const uint4*)(u + idx);
    const __bf16* gp = (const __bf16*)&gv;
    const __bf16* up = (const __bf16*)&uv;
    __bf16 o[8];
    #pragma unroll
    for (int j = 0; j < 8; ++j) {
        float x = (float)gp[j];
        float y = x / (1.f + __expf(-x)) * (float)up[j];
        o[j] = (__bf16)y;
    }
    *(uint4*)(h + idx) = *(const uint4*)o;
}

// ============ core 128x128 MFMA GEMM (m97 structure, global_load_lds) ======
// C[base+r, n0..] = sum_k A[row(r), k] * BT[n, k], all bf16, K-contiguous.
// NK = K/32 steps. LDS: As[2][128][32] + Bs[2][128][32] bf16 = 32KB; smem 36KB.
template<int NK, bool GATHER>
__device__ __forceinline__ void gemm_core(char* __restrict__ smem,
    const __bf16* __restrict__ A, int lda,
    const __bf16* __restrict__ BT, int ldb,
    __bf16* __restrict__ C, int ldc,
    int rows, int base, const int* __restrict__ tok, int m0, int n0)
{
    const int tid  = threadIdx.x;
    const int lane = tid & 63;
    const int wid  = tid >> 6;           // 4 waves, 2x2 grid of 64x64
    const int wr   = wid >> 1, wc = wid & 1;

    // ---- staging map: wave instr s (2 per operand) covers rows [(wid*2+s)*16, +16)
    // lane l -> row (l>>2), chunk (l&3); source chunk XOR-swizzled: cs = c ^ (r&3)
    const int rs0 = (wid*2 + 0)*16 + (lane >> 2);
    const int rs1 = (wid*2 + 1)*16 + (lane >> 2);
    const int cch = lane & 3;
    int ga0 = m0 + rs0, ga1 = m0 + rs1;
    int ar0, ar1;
    if (GATHER) {
        ar0 = tok[base + (ga0 < rows ? ga0 : 0)];
        ar1 = tok[base + (ga1 < rows ? ga1 : 0)];
    } else {
        ar0 = base + (ga0 < rows ? ga0 : 0);
        ar1 = base + (ga1 < rows ? ga1 : 0);
    }
    const __bf16* a0p = A  + (size_t)ar0 * lda + (cch ^ (rs0 & 3)) * 8;
    const __bf16* a1p = A  + (size_t)ar1 * lda + (cch ^ (rs1 & 3)) * 8;
    const __bf16* b0p = BT + (size_t)(n0 + rs0) * ldb + (cch ^ (rs0 & 3)) * 8;
    const __bf16* b1p = BT + (size_t)(n0 + rs1) * ldb + (cch ^ (rs1 & 3)) * 8;
    char* lA0 = smem + (wid*2 + 0) * 1024;   // 16 rows * 64B
    char* lA1 = smem + (wid*2 + 1) * 1024;

#define STAGE(b, t)                                             \
    {                                                           \
        GLDS(a0p + (t)*32, lA0 + (b)*8192);                     \
        GLDS(a1p + (t)*32, lA1 + (b)*8192);                     \
        GLDS(b0p + (t)*32, lA0 + 16384 + (b)*8192);             \
        GLDS(b1p + (t)*32, lA1 + 16384 + (b)*8192);             \
    }

    // ---- fragment read offsets (bytes), same XOR on read side
    const int fr = lane & 15, fq = lane >> 4;
    const int aoff = ((wr*64 + fr)*32 + ((fq ^ (fr & 3)) * 8)) * 2;
    const int boff = ((wc*64 + fr)*32 + ((fq ^ (fr & 3)) * 8)) * 2;

    f32x4 acc[4][4];
    #pragma unroll
    for (int i = 0; i < 4; ++i)
        #pragma unroll
        for (int j = 0; j < 4; ++j) acc[i][j] = f32x4{0.f,0.f,0.f,0.f};

    STAGE(0, 0);
    asm volatile("s_waitcnt vmcnt(0)" ::: "memory");
    __builtin_amdgcn_s_barrier();

    #pragma unroll 1
    for (int t = 0; t < NK; ++t) {
        int nt = (t + 1 < NK) ? t + 1 : NK - 1;      // clamped (harmless re-stage)
        STAGE((t + 1) & 1, nt);                       // async into other buffer
        asm volatile("s_waitcnt vmcnt(4)" ::: "memory");  // tile t's 4 DMAs done
        __builtin_amdgcn_s_barrier();

        const char* Ab = smem + (t & 1) * 8192;
        const char* Bb = smem + 16384 + (t & 1) * 8192;
        bf16x8 af[4], bfr[4];
        #pragma unroll
        for (int m = 0; m < 4; ++m) af[m]  = *(const bf16x8*)(Ab + aoff + m*1024);
        #pragma unroll
        for (int n = 0; n < 4; ++n) bfr[n] = *(const bf16x8*)(Bb + boff + n*1024);
        __builtin_amdgcn_s_setprio(1);
        #pragma unroll
        for (int m = 0; m < 4; ++m)
            #pragma unroll
            for (int n = 0; n < 4; ++n)
                acc[m][n] = __builtin_amdgcn_mfma_f32_16x16x32_bf16(af[m], bfr[n], acc[m][n], 0, 0, 0);
        __builtin_amdgcn_s_setprio(0);
        asm volatile("s_waitcnt lgkmcnt(0)" ::: "memory");  // reads of buf done
        __builtin_amdgcn_s_barrier();
    }
#undef STAGE

    // ---- epilogue: per-wave LDS transpose (bf16), coalesced 16B row stores
    asm volatile("s_waitcnt vmcnt(0) lgkmcnt(0)" ::: "memory");  // drain stray DMA
    __builtin_amdgcn_s_barrier();

    __bf16* ep = (__bf16*)(smem + wid * 9216);   // 64 rows x 72 bf16 (144B, 16B-aligned)
    #pragma unroll
    for (int m = 0; m < 4; ++m)
        #pragma unroll
        for (int n = 0; n < 4; ++n)
            #pragma unroll
            for (int q = 0; q < 4; ++q)
                ep[(m*16 + fq*4 + q)*72 + n*16 + fr] = (__bf16)acc[m][n][q];

    const int grow = m0 + wr*64 + lane;
    if (grow < rows) {
        __bf16* cp = C + (size_t)(base + grow) * ldc + n0 + wc*64;
        const __bf16* rp = ep + lane * 72;
        #pragma unroll
        for (int j = 0; j < 8; ++j)
            *(uint4*)(cp + j*8) = *(const uint4*)(rp + j*8);
    }
}

// ---------------- phase 1/2 wrapper: expert (z<8) + shared (z=8) -----------
__launch_bounds__(256, 4)
__global__ void gemm_p1(const __bf16* __restrict__ xbf,
                        const __bf16* __restrict__ WeT, const __bf16* __restrict__ WsT,
                        __bf16* __restrict__ Ce, __bf16* __restrict__ Cs,
                        const int* __restrict__ cnt, const int* __restrict__ offe,
                        const int* __restrict__ tok)
{
    __shared__ alignas(16) char smem[36864];
    int z = blockIdx.z;
    if (z < 8) {
        if (blockIdx.x >= NI/128) return;       // 11 n-tiles
        int rows = cnt[z], base = offe[z];
        int m0 = blockIdx.y * 128; if (m0 >= rows) return;
        gemm_core<NH/32, true>(smem, xbf, NH, WeT + (size_t)z * NH * NI, NH,
                               Ce, NI, rows, base, tok, m0, blockIdx.x * 128);
    } else {
        gemm_core<NH/32, false>(smem, xbf, NH, WsT, NH,
                                Cs, NIS, NT, 0, nullptr, blockIdx.y * 128, blockIdx.x * 128);
    }
}

// ---------------- phase 3 wrapper: expert down (z<8) + shared down splitK (z=8..11)
__launch_bounds__(256, 4)
__global__ void gemm_p3(const __bf16* __restrict__ hbf, const __bf16* __restrict__ shbf,
                        const __bf16* __restrict__ WdT, const __bf16* __restrict__ WsdT,
                        __bf16* __restrict__ pair, __bf16* __restrict__ shp,
                        const int* __restrict__ cnt, const int* __restrict__ offe)
{
    __shared__ alignas(16) char smem[36864];
    int z = blockIdx.z;
    if (z < 8) {
        int rows = cnt[z], base = offe[z];
        int m0 = blockIdx.y * 128; if (m0 >= rows) return;
        gemm_core<NI/32, false>(smem, hbf, NI, WdT + (size_t)z * NH * NI, NI,
                                pair, NH, rows, base, nullptr, m0, blockIdx.x * 128);
    } else {
        int q = z - 8;                           // K-quarter
        gemm_core<NI/32, false>(smem, shbf + q * NI, NIS, WsdT + q * NI, NIS,
                                shp + (size_t)q * NT * NH, NH,
                                NT, 0, nullptr, blockIdx.y * 128, blockIdx.x * 128);
    }
}

// ---------------- final combine ----------------
__global__ void combine_kernel(const float* __restrict__ x, const float* __restrict__ shexp_w,
                               const __bf16* __restrict__ shp, const __bf16* __restrict__ pair_out,
                               const int* __restrict__ slot, const float* __restrict__ wts,
                               float* __restrict__ out)
{
    int t = blockIdx.x;
    int tid = threadIdx.x;
    const float* xr = x + (size_t)t * NH;

    float p = 0.f;
    #pragma unroll
    for (int j = 0; j < 8; ++j) {
        int k = tid * 8 + j;
        p += xr[k] * shexp_w[k];
    }
    __shared__ float red[256];
    red[tid] = p;
    __syncthreads();
    for (int s = 128; s > 0; s >>= 1) {
        if (tid < s) red[tid] += red[tid + s];
        __syncthreads();
    }
    float sig = 1.f / (1.f + expf(-red[0]));

    int   s0 = slot[2*t],   s1 = slot[2*t+1];
    float w0 = wts[2*t],    w1 = wts[2*t+1];
    const __bf16* pr0 = pair_out + (size_t)s0 * NH;
    const __bf16* pr1 = pair_out + (size_t)s1 * NH;
    const __bf16* sd  = shp + (size_t)t * NH;
    float* orow = out + (size_t)t * NH;
    const size_t PS = (size_t)NT * NH;
    for (int n = tid; n < NH; n += 256) {
        float sdv = (float)sd[n] + (float)sd[n + PS] + (float)sd[n + 2*PS] + (float)sd[n + 3*PS];
        orow[n] = sdv * sig + w0 * (float)pr0[n] + w1 * (float)pr1[n];
    }
}

// ---------------- launch ----------------
extern "C" void kernel_launch(void* const* d_in, const int* in_sizes, int n_in,
                              void* d_out, int out_size, void* d_ws, size_t ws_size,
                              hipStream_t stream)
{
    const float* x       = (const float*)d_in[0];
    const float* gate_w  = (const float*)d_in[1];
    const float* w_gate  = (const float*)d_in[2];
    const float* w_up    = (const float*)d_in[3];
    const float* w_down  = (const float*)d_in[4];
    const float* sh_gate = (const float*)d_in[5];
    const float* sh_up   = (const float*)d_in[6];
    const float* sh_down = (const float*)d_in[7];
    const float* shexp_g = (const float*)d_in[8];

    float* out        = (float*)d_out;
    float* out_logits = out + (size_t)NT * NH;

    char* ws = (char*)d_ws;
    __bf16* xbf  = (__bf16*)(ws + WS_XBF);
    int*    sel  = (int*)  (ws + WS_SEL);
    float*  wts  = (float*)(ws + WS_WTS);
    int*    cnt  = (int*)  (ws + WS_CNT);
    int*    offe = (int*)  (ws + WS_OFFE);
    int*    tok  = (int*)  (ws + WS_TOK);
    float*  pwt  = (float*)(ws + WS_PWT);
    int*    slot = (int*)  (ws + WS_SLOT);
    __bf16* gbuf = (__bf16*)(ws + WS_G);
    __bf16* ubuf = (__bf16*)(ws + WS_U);
    __bf16* hbf  = (__bf16*)(ws + WS_HBF);
    __bf16* pair = (__bf16*)(ws + WS_PAIR);
    __bf16* shg  = (__bf16*)(ws + WS_SHG);
    __bf16* shu  = (__bf16*)(ws + WS_SHU);
    __bf16* shbf = (__bf16*)(ws + WS_SHBF);
    __bf16* shp  = (__bf16*)(ws + WS_SHP);
    __bf16* WeT  = (__bf16*)(ws + WS_WE);    // expert weight^T region (reused 3x)
    __bf16* WsT  = (__bf16*)(ws + WS_WS2);   // shared weight^T region (reused 3x)
    (void)pwt; (void)in_sizes; (void)n_in; (void)out_size; (void)ws_size;

    router_kernel<<<dim3(16), dim3(256), 0, stream>>>(x, gate_w, out_logits, sel, wts);
    bucket_kernel<<<dim3(1), dim3(512), 0, stream>>>(sel, wts, cnt, offe, tok, pwt, slot);
    cast_kernel<<<dim3(1024), dim3(256), 0, stream>>>(x, xbf, (long long)NT * NH);

    // ---- gate round: convert w_gate (8x [2048][1408]) + sh_gate ([2048][5632])
    conv_kernel<<<dim3(88, 32, 9), dim3(256), 0, stream>>>(
        w_gate, WeT, NH, NI, 8, (size_t)NH * NI, sh_gate, WsT, NH, NIS);
    gemm_p1<<<dim3(44, 4, 9), dim3(256), 0, stream>>>(
        xbf, WeT, WsT, gbuf, shg, cnt, offe, tok);

    // ---- up round
    conv_kernel<<<dim3(88, 32, 9), dim3(256), 0, stream>>>(
        w_up, WeT, NH, NI, 8, (size_t)NH * NI, sh_up, WsT, NH, NIS);
    gemm_p1<<<dim3(44, 4, 9), dim3(256), 0, stream>>>(
        xbf, WeT, WsT, ubuf, shu, cnt, offe, tok);

    // ---- silu
    silu_fused_kernel<<<dim3(2112), dim3(256), 0, stream>>>(
        gbuf, ubuf, hbf, (long long)1024 * NI,
        shg, shu, shbf, (long long)NT * NIS);

    // ---- down round: w_down (8x [1408][2048]) + sh_down ([5632][2048])
    conv_kernel<<<dim3(32, 88, 9), dim3(256), 0, stream>>>(
        w_down, WeT, NI, NH, 8, (size_t)NI * NH, sh_down, WsT, NIS, NH);
    gemm_p3<<<dim3(16, 4, 12), dim3(256), 0, stream>>>(
        hbf, shbf, WeT, WsT, pair, shp, cnt, offe);

    combine_kernel<<<dim3(NT), dim3(256), 0, stream>>>(
        x, shexp_g, shp, pair, slot, wts, out);
}

// Round 9
// 331.092 us; speedup vs baseline: 1.5919x; 1.2070x over previous
//
#include <hip/hip_runtime.h>
#include <hip/hip_bf16.h>

// ---------------- problem dims ----------------
#define NT  512      // tokens
#define NH  2048     // hidden
#define NE  8        // experts
#define NI  1408     // expert intermediate
#define NIS 5632     // shared intermediate

typedef __bf16 bf16x8 __attribute__((ext_vector_type(8)));
typedef float  f32x4  __attribute__((ext_vector_type(4)));

// async global->LDS DMA, 16B per lane, wave-uniform LDS base + lane*16
#define GLDS(gp, lp) __builtin_amdgcn_global_load_lds( \
    (const __attribute__((address_space(1))) void*)(gp), \
    (__attribute__((address_space(3))) void*)(lp), 16, 0, 0)

// ---------------- workspace layout (bytes) ----------------
static constexpr size_t WS_XBF  = 0;                                  // 512*2048 bf16
static constexpr size_t WS_SEL  = WS_XBF + (size_t)NT*NH*2;           // 1024 int
static constexpr size_t WS_WTS  = WS_SEL + 4096;
static constexpr size_t WS_CNT  = WS_WTS + 4096;
static constexpr size_t WS_OFFE = WS_CNT + 32;
static constexpr size_t WS_TOK  = WS_OFFE + 32;
static constexpr size_t WS_PWT  = WS_TOK + 4096;
static constexpr size_t WS_SLOT = WS_PWT + 4096;
static constexpr size_t WS_G    = WS_SLOT + 4096;                     // 1024*1408 bf16
static constexpr size_t WS_U    = WS_G   + (size_t)1024*NI*2;
static constexpr size_t WS_HBF  = WS_U   + (size_t)1024*NI*2;         // 1024*1408 bf16
static constexpr size_t WS_PAIR = WS_HBF + (size_t)1024*NI*2;         // 1024*2048 bf16
static constexpr size_t WS_SHG  = WS_PAIR+ (size_t)1024*NH*2;         // 512*5632 bf16
static constexpr size_t WS_SHU  = WS_SHG + (size_t)NT*NIS*2;
static constexpr size_t WS_SHBF = WS_SHU + (size_t)NT*NIS*2;
static constexpr size_t WS_SHP  = WS_SHBF+ (size_t)NT*NIS*2;          // 4*512*2048 bf16
static constexpr size_t WS_WE   = WS_SHP + (size_t)4*NT*NH*2;         // 8*2048*1408 bf16 (reused 3x)
static constexpr size_t WS_WS2  = WS_WE  + (size_t)NE*NH*NI*2;        // 5632*2048 bf16 (reused 3x)

// ---------------- router: one wave per token ----------------
// lane l: expert e = l&7, k-chunk c = l>>3 (256 elems). shfl_xor k-reduce.
__global__ void router_kernel(const float* __restrict__ x, const float* __restrict__ gw,
                              float* __restrict__ out_logits,
                              int* __restrict__ sel, float* __restrict__ wts)
{
    int w    = threadIdx.x >> 6;
    int lane = threadIdx.x & 63;
    int t    = blockIdx.x * 4 + w;
    int e    = lane & 7, c = lane >> 3;
    const float* xr = x  + (size_t)t * NH + c * 256;
    const float* gr = gw + (size_t)e * NH + c * 256;
    float acc = 0.f;
    #pragma unroll 8
    for (int it = 0; it < 64; ++it) {
        float4 xv = *(const float4*)(xr + it*4);
        float4 gv = *(const float4*)(gr + it*4);
        acc += xv.x*gv.x + xv.y*gv.y + xv.z*gv.z + xv.w*gv.w;
    }
    acc += __shfl_xor(acc, 8);
    acc += __shfl_xor(acc, 16);
    acc += __shfl_xor(acc, 32);
    if (lane < 8) out_logits[(size_t)t * NE + e] = acc;

    float l[8];
    #pragma unroll
    for (int j = 0; j < 8; ++j) l[j] = __shfl(acc, j);   // lane j (<8) holds expert j
    if (lane == 0) {
        int i1 = 0;
        #pragma unroll
        for (int j = 1; j < 8; ++j) if (l[j] > l[i1]) i1 = j;
        int i2 = -1;
        #pragma unroll
        for (int j = 0; j < 8; ++j) {
            if (j == i1) continue;
            if (i2 < 0 || l[j] > l[i2]) i2 = j;
        }
        float d  = expf(l[i2] - l[i1]);
        float w1 = 1.f / (1.f + d);
        float w2 = 1.f - w1;
        sel[2*t]   = i1;  sel[2*t+1] = i2;
        wts[2*t]   = w1;  wts[2*t+1] = w2;
    }
}

// ---------------- wave-parallel deterministic bucketing ----------------
__global__ void bucket_kernel(const int* __restrict__ sel, const float* __restrict__ wts,
                              int* __restrict__ cnt, int* __restrict__ offe,
                              int* __restrict__ tok, float* __restrict__ pwt,
                              int* __restrict__ slot)
{
    int tid  = threadIdx.x;          // 0..511
    int wid  = tid >> 6;             // expert id
    int lane = tid & 63;
    __shared__ int scnt[8], soff[8];

    unsigned long long masks[16];
    int total = 0;
    #pragma unroll
    for (int c = 0; c < 16; ++c) {
        int idx = c * 64 + lane;
        int s = sel[idx];
        unsigned long long m = __ballot(s == wid);
        masks[c] = m;
        total += __popcll(m);
    }
    if (lane == 0) { scnt[wid] = total; cnt[wid] = total; }
    __syncthreads();
    if (tid == 0) {
        int s = 0;
        #pragma unroll
        for (int j = 0; j < 8; ++j) { soff[j] = s; offe[j] = s; s += scnt[j]; }
    }
    __syncthreads();
    int pfx = soff[wid];
    unsigned long long below = (lane == 63) ? ~0ull >> 1 : ((1ull << lane) - 1);
    #pragma unroll
    for (int c = 0; c < 16; ++c) {
        int idx = c * 64 + lane;
        unsigned long long m = masks[c];
        if ((m >> lane) & 1ull) {
            int rank = pfx + (int)__popcll(m & below);
            tok[rank]  = idx >> 1;
            pwt[rank]  = wts[idx];
            slot[idx]  = rank;
        }
        pfx += (int)__popcll(m);
    }
}

// ---------------- fp32 -> bf16 cast (activations) ----------------
__global__ void cast_kernel(const float* __restrict__ src, __bf16* __restrict__ dst, long long n)
{
    long long i = ((long long)blockIdx.x * blockDim.x + threadIdx.x) * 4;
    if (i >= n) return;
    float4 v = *(const float4*)(src + i);
    __bf16 o[4] = { (__bf16)v.x, (__bf16)v.y, (__bf16)v.z, (__bf16)v.w };
    *(uint2*)(dst + i) = *(const uint2*)o;
}

// ---------------- weight convert+transpose: f32 [K][N] -> bf16 [N][K] -------
__global__ void conv_kernel(const float* __restrict__ srcA, __bf16* __restrict__ dstA,
                            int KA, int NA, int nzA, size_t sstrA,
                            const float* __restrict__ srcB, __bf16* __restrict__ dstB,
                            int KB, int NB)
{
    int z = blockIdx.z;
    const float* src; __bf16* dst; int K, N;
    if (z < nzA) { src = srcA + sstrA * z; dst = dstA + sstrA * z; K = KA; N = NA; }
    else         { src = srcB;             dst = dstB;             K = KB; N = NB; }
    int nt = blockIdx.x, kt = blockIdx.y;
    if (nt * 64 >= N || kt * 64 >= K) return;

    __shared__ float ls[64][65];
    int tid = threadIdx.x;
    int n4 = tid & 15, kr = tid >> 4;
    #pragma unroll
    for (int p = 0; p < 4; ++p) {
        int k = p * 16 + kr;
        float4 v = *(const float4*)(src + (size_t)(kt*64 + k) * N + nt*64 + n4*4);
        ls[k][n4*4+0] = v.x; ls[k][n4*4+1] = v.y; ls[k][n4*4+2] = v.z; ls[k][n4*4+3] = v.w;
    }
    __syncthreads();
    int nl = tid >> 2, kq = tid & 3;
    __bf16 o[16];
    #pragma unroll
    for (int i = 0; i < 16; ++i) o[i] = (__bf16)ls[kq*16 + i][nl];
    __bf16* dp = dst + (size_t)(nt*64 + nl) * K + kt*64 + kq*16;
    *(uint4*)(dp)     = ((const uint4*)o)[0];
    *(uint4*)(dp + 8) = ((const uint4*)o)[1];
}

// ---------------- fused silu(g)*u (bf16 in/out) ----------------
__global__ void silu_fused_kernel(const __bf16* __restrict__ g1, const __bf16* __restrict__ u1,
                                  __bf16* __restrict__ h1, long long n1,
                                  const __bf16* __restrict__ g2, const __bf16* __restrict__ u2,
                                  __bf16* __restrict__ h2, long long n2)
{
    long long i = ((long long)blockIdx.x * blockDim.x + threadIdx.x) * 8;
    const __bf16 *g, *u; __bf16* h; long long idx;
    if (i < n1)           { g = g1; u = u1; h = h1; idx = i; }
    else if (i < n1 + n2) { g = g2; u = u2; h = h2; idx = i - n1; }
    else return;
    uint4 gv = *(const uint4*)(g + idx);
    uint4 uv = *(const uint4*)(u + idx);
    const __bf16* gp = (const __bf16*)&gv;
    const __bf16* up = (const __bf16*)&uv;
    __bf16 o[8];
    #pragma unroll
    for (int j = 0; j < 8; ++j) {
        float x = (float)gp[j];
        float y = x / (1.f + __expf(-x)) * (float)up[j];
        o[j] = (__bf16)y;
    }
    *(uint4*)(h + idx) = *(const uint4*)o;
}

// ============ core 128x128 MFMA GEMM (m97 structure, global_load_lds) ======
template<int NK, bool GATHER>
__device__ __forceinline__ void gemm_core(char* __restrict__ smem,
    const __bf16* __restrict__ A, int lda,
    const __bf16* __restrict__ BT, int ldb,
    __bf16* __restrict__ C, int ldc,
    int rows, int base, const int* __restrict__ tok, int m0, int n0)
{
    const int tid  = threadIdx.x;
    const int lane = tid & 63;
    const int wid  = tid >> 6;           // 4 waves, 2x2 grid of 64x64
    const int wr   = wid >> 1, wc = wid & 1;

    const int rs0 = (wid*2 + 0)*16 + (lane >> 2);
    const int rs1 = (wid*2 + 1)*16 + (lane >> 2);
    const int cch = lane & 3;
    int ga0 = m0 + rs0, ga1 = m0 + rs1;
    int ar0, ar1;
    if (GATHER) {
        ar0 = tok[base + (ga0 < rows ? ga0 : 0)];
        ar1 = tok[base + (ga1 < rows ? ga1 : 0)];
    } else {
        ar0 = base + (ga0 < rows ? ga0 : 0);
        ar1 = base + (ga1 < rows ? ga1 : 0);
    }
    const __bf16* a0p = A  + (size_t)ar0 * lda + (cch ^ (rs0 & 3)) * 8;
    const __bf16* a1p = A  + (size_t)ar1 * lda + (cch ^ (rs1 & 3)) * 8;
    const __bf16* b0p = BT + (size_t)(n0 + rs0) * ldb + (cch ^ (rs0 & 3)) * 8;
    const __bf16* b1p = BT + (size_t)(n0 + rs1) * ldb + (cch ^ (rs1 & 3)) * 8;
    char* lA0 = smem + (wid*2 + 0) * 1024;   // 16 rows * 64B
    char* lA1 = smem + (wid*2 + 1) * 1024;

#define STAGE(b, t)                                             \
    {                                                           \
        GLDS(a0p + (t)*32, lA0 + (b)*8192);                     \
        GLDS(a1p + (t)*32, lA1 + (b)*8192);                     \
        GLDS(b0p + (t)*32, lA0 + 16384 + (b)*8192);             \
        GLDS(b1p + (t)*32, lA1 + 16384 + (b)*8192);             \
    }

    const int fr = lane & 15, fq = lane >> 4;
    const int aoff = ((wr*64 + fr)*32 + ((fq ^ (fr & 3)) * 8)) * 2;
    const int boff = ((wc*64 + fr)*32 + ((fq ^ (fr & 3)) * 8)) * 2;

    f32x4 acc[4][4];
    #pragma unroll
    for (int i = 0; i < 4; ++i)
        #pragma unroll
        for (int j = 0; j < 4; ++j) acc[i][j] = f32x4{0.f,0.f,0.f,0.f};

    STAGE(0, 0);
    asm volatile("s_waitcnt vmcnt(0)" ::: "memory");
    __builtin_amdgcn_s_barrier();

    #pragma unroll 1
    for (int t = 0; t < NK; ++t) {
        int nt = (t + 1 < NK) ? t + 1 : NK - 1;      // clamped (harmless re-stage)
        STAGE((t + 1) & 1, nt);                       // async into other buffer
        asm volatile("s_waitcnt vmcnt(4)" ::: "memory");  // tile t's 4 DMAs done
        __builtin_amdgcn_s_barrier();

        const char* Ab = smem + (t & 1) * 8192;
        const char* Bb = smem + 16384 + (t & 1) * 8192;
        bf16x8 af[4], bfr[4];
        #pragma unroll
        for (int m = 0; m < 4; ++m) af[m]  = *(const bf16x8*)(Ab + aoff + m*1024);
        #pragma unroll
        for (int n = 0; n < 4; ++n) bfr[n] = *(const bf16x8*)(Bb + boff + n*1024);
        __builtin_amdgcn_s_setprio(1);
        #pragma unroll
        for (int m = 0; m < 4; ++m)
            #pragma unroll
            for (int n = 0; n < 4; ++n)
                acc[m][n] = __builtin_amdgcn_mfma_f32_16x16x32_bf16(af[m], bfr[n], acc[m][n], 0, 0, 0);
        __builtin_amdgcn_s_setprio(0);
        asm volatile("s_waitcnt lgkmcnt(0)" ::: "memory");  // reads of buf done
        __builtin_amdgcn_s_barrier();
    }
#undef STAGE

    asm volatile("s_waitcnt vmcnt(0) lgkmcnt(0)" ::: "memory");
    __builtin_amdgcn_s_barrier();

    __bf16* ep = (__bf16*)(smem + wid * 9216);   // 64 rows x 72 bf16
    #pragma unroll
    for (int m = 0; m < 4; ++m)
        #pragma unroll
        for (int n = 0; n < 4; ++n)
            #pragma unroll
            for (int q = 0; q < 4; ++q)
                ep[(m*16 + fq*4 + q)*72 + n*16 + fr] = (__bf16)acc[m][n][q];

    const int grow = m0 + wr*64 + lane;
    if (grow < rows) {
        __bf16* cp = C + (size_t)(base + grow) * ldc + n0 + wc*64;
        const __bf16* rp = ep + lane * 72;
        #pragma unroll
        for (int j = 0; j < 8; ++j)
            *(uint4*)(cp + j*8) = *(const uint4*)(rp + j*8);
    }
}

// ---------------- phase 1/2 wrapper: expert (z<8) + shared (z=8) -----------
__launch_bounds__(256, 4)
__global__ void gemm_p1(const __bf16* __restrict__ xbf,
                        const __bf16* __restrict__ WeT, const __bf16* __restrict__ WsT,
                        __bf16* __restrict__ Ce, __bf16* __restrict__ Cs,
                        const int* __restrict__ cnt, const int* __restrict__ offe,
                        const int* __restrict__ tok)
{
    __shared__ alignas(16) char smem[36864];
    int z = blockIdx.z;
    if (z < 8) {
        if (blockIdx.x >= NI/128) return;       // 11 n-tiles
        int rows = cnt[z], base = offe[z];
        int m0 = blockIdx.y * 128; if (m0 >= rows) return;
        gemm_core<NH/32, true>(smem, xbf, NH, WeT + (size_t)z * NH * NI, NH,
                               Ce, NI, rows, base, tok, m0, blockIdx.x * 128);
    } else {
        gemm_core<NH/32, false>(smem, xbf, NH, WsT, NH,
                                Cs, NIS, NT, 0, nullptr, blockIdx.y * 128, blockIdx.x * 128);
    }
}

// ---------------- phase 3 wrapper: expert down (z<8) + shared down splitK (z=8..11)
__launch_bounds__(256, 4)
__global__ void gemm_p3(const __bf16* __restrict__ hbf, const __bf16* __restrict__ shbf,
                        const __bf16* __restrict__ WdT, const __bf16* __restrict__ WsdT,
                        __bf16* __restrict__ pair, __bf16* __restrict__ shp,
                        const int* __restrict__ cnt, const int* __restrict__ offe)
{
    __shared__ alignas(16) char smem[36864];
    int z = blockIdx.z;
    if (z < 8) {
        int rows = cnt[z], base = offe[z];
        int m0 = blockIdx.y * 128; if (m0 >= rows) return;
        gemm_core<NI/32, false>(smem, hbf, NI, WdT + (size_t)z * NH * NI, NI,
                                pair, NH, rows, base, nullptr, m0, blockIdx.x * 128);
    } else {
        int q = z - 8;                           // K-quarter
        gemm_core<NI/32, false>(smem, shbf + q * NI, NIS, WsdT + q * NI, NIS,
                                shp + (size_t)q * NT * NH, NH,
                                NT, 0, nullptr, blockIdx.y * 128, blockIdx.x * 128);
    }
}

// ---------------- final combine ----------------
__global__ void combine_kernel(const float* __restrict__ x, const float* __restrict__ shexp_w,
                               const __bf16* __restrict__ shp, const __bf16* __restrict__ pair_out,
                               const int* __restrict__ slot, const float* __restrict__ wts,
                               float* __restrict__ out)
{
    int t = blockIdx.x;
    int tid = threadIdx.x;
    const float* xr = x + (size_t)t * NH;

    float p = 0.f;
    #pragma unroll
    for (int j = 0; j < 8; ++j) {
        int k = tid * 8 + j;
        p += xr[k] * shexp_w[k];
    }
    __shared__ float red[256];
    red[tid] = p;
    __syncthreads();
    for (int s = 128; s > 0; s >>= 1) {
        if (tid < s) red[tid] += red[tid + s];
        __syncthreads();
    }
    float sig = 1.f / (1.f + expf(-red[0]));

    int   s0 = slot[2*t],   s1 = slot[2*t+1];
    float w0 = wts[2*t],    w1 = wts[2*t+1];
    const __bf16* pr0 = pair_out + (size_t)s0 * NH;
    const __bf16* pr1 = pair_out + (size_t)s1 * NH;
    const __bf16* sd  = shp + (size_t)t * NH;
    float* orow = out + (size_t)t * NH;
    const size_t PS = (size_t)NT * NH;
    for (int n = tid; n < NH; n += 256) {
        float sdv = (float)sd[n] + (float)sd[n + PS] + (float)sd[n + 2*PS] + (float)sd[n + 3*PS];
        orow[n] = sdv * sig + w0 * (float)pr0[n] + w1 * (float)pr1[n];
    }
}

// ---------------- launch ----------------
extern "C" void kernel_launch(void* const* d_in, const int* in_sizes, int n_in,
                              void* d_out, int out_size, void* d_ws, size_t ws_size,
                              hipStream_t stream)
{
    const float* x       = (const float*)d_in[0];
    const float* gate_w  = (const float*)d_in[1];
    const float* w_gate  = (const float*)d_in[2];
    const float* w_up    = (const float*)d_in[3];
    const float* w_down  = (const float*)d_in[4];
    const float* sh_gate = (const float*)d_in[5];
    const float* sh_up   = (const float*)d_in[6];
    const float* sh_down = (const float*)d_in[7];
    const float* shexp_g = (const float*)d_in[8];

    float* out        = (float*)d_out;
    float* out_logits = out + (size_t)NT * NH;

    char* ws = (char*)d_ws;
    __bf16* xbf  = (__bf16*)(ws + WS_XBF);
    int*    sel  = (int*)  (ws + WS_SEL);
    float*  wts  = (float*)(ws + WS_WTS);
    int*    cnt  = (int*)  (ws + WS_CNT);
    int*    offe = (int*)  (ws + WS_OFFE);
    int*    tok  = (int*)  (ws + WS_TOK);
    float*  pwt  = (float*)(ws + WS_PWT);
    int*    slot = (int*)  (ws + WS_SLOT);
    __bf16* gbuf = (__bf16*)(ws + WS_G);
    __bf16* ubuf = (__bf16*)(ws + WS_U);
    __bf16* hbf  = (__bf16*)(ws + WS_HBF);
    __bf16* pair = (__bf16*)(ws + WS_PAIR);
    __bf16* shg  = (__bf16*)(ws + WS_SHG);
    __bf16* shu  = (__bf16*)(ws + WS_SHU);
    __bf16* shbf = (__bf16*)(ws + WS_SHBF);
    __bf16* shp  = (__bf16*)(ws + WS_SHP);
    __bf16* WeT  = (__bf16*)(ws + WS_WE);    // expert weight^T region (reused 3x)
    __bf16* WsT  = (__bf16*)(ws + WS_WS2);   // shared weight^T region (reused 3x)
    (void)pwt; (void)in_sizes; (void)n_in; (void)out_size; (void)ws_size;

    router_kernel<<<dim3(128), dim3(256), 0, stream>>>(x, gate_w, out_logits, sel, wts);
    bucket_kernel<<<dim3(1), dim3(512), 0, stream>>>(sel, wts, cnt, offe, tok, pwt, slot);
    cast_kernel<<<dim3(1024), dim3(256), 0, stream>>>(x, xbf, (long long)NT * NH);

    // ---- gate round: convert w_gate (8x [2048][1408]) + sh_gate ([2048][5632])
    conv_kernel<<<dim3(88, 32, 9), dim3(256), 0, stream>>>(
        w_gate, WeT, NH, NI, 8, (size_t)NH * NI, sh_gate, WsT, NH, NIS);
    gemm_p1<<<dim3(44, 4, 9), dim3(256), 0, stream>>>(
        xbf, WeT, WsT, gbuf, shg, cnt, offe, tok);

    // ---- up round
    conv_kernel<<<dim3(88, 32, 9), dim3(256), 0, stream>>>(
        w_up, WeT, NH, NI, 8, (size_t)NH * NI, sh_up, WsT, NH, NIS);
    gemm_p1<<<dim3(44, 4, 9), dim3(256), 0, stream>>>(
        xbf, WeT, WsT, ubuf, shu, cnt, offe, tok);

    // ---- silu
    silu_fused_kernel<<<dim3(2112), dim3(256), 0, stream>>>(
        gbuf, ubuf, hbf, (long long)1024 * NI,
        shg, shu, shbf, (long long)NT * NIS);

    // ---- down round: w_down (8x [1408][2048]) + sh_down ([5632][2048])
    conv_kernel<<<dim3(32, 88, 9), dim3(256), 0, stream>>>(
        w_down, WeT, NI, NH, 8, (size_t)NI * NH, sh_down, WsT, NIS, NH);
    gemm_p3<<<dim3(16, 4, 12), dim3(256), 0, stream>>>(
        hbf, shbf, WeT, WsT, pair, shp, cnt, offe);

    combine_kernel<<<dim3(NT), dim3(256), 0, stream>>>(
        x, shexp_g, shp, pair, slot, wts, out);
}

// Round 10
// 224.226 us; speedup vs baseline: 2.3506x; 1.4766x over previous
//
#include <hip/hip_runtime.h>
#include <hip/hip_bf16.h>

// ---------------- problem dims ----------------
#define NT  512      // tokens
#define NH  2048     // hidden
#define NE  8        // experts
#define NI  1408     // expert intermediate
#define NIS 5632     // shared intermediate

typedef __bf16 bf16x8 __attribute__((ext_vector_type(8)));
typedef float  f32x4  __attribute__((ext_vector_type(4)));

// async global->LDS DMA, 16B per lane, wave-uniform LDS base + lane*16
#define GLDS(gp, lp) __builtin_amdgcn_global_load_lds( \
    (const __attribute__((address_space(1))) void*)(gp), \
    (__attribute__((address_space(3))) void*)(lp), 16, 0, 0)

// ---------------- workspace layout (bytes) ----------------
static constexpr size_t WS_XBF  = 0;                                  // 512*2048 bf16
static constexpr size_t WS_SEL  = WS_XBF + (size_t)NT*NH*2;           // 1024 int
static constexpr size_t WS_WTS  = WS_SEL + 4096;
static constexpr size_t WS_CNT  = WS_WTS + 4096;
static constexpr size_t WS_OFFE = WS_CNT + 32;
static constexpr size_t WS_TOK  = WS_OFFE + 32;
static constexpr size_t WS_PWT  = WS_TOK + 4096;
static constexpr size_t WS_SLOT = WS_PWT + 4096;
static constexpr size_t WS_G    = WS_SLOT + 4096;                     // 1024*1408 bf16
static constexpr size_t WS_U    = WS_G   + (size_t)1024*NI*2;
static constexpr size_t WS_HBF  = WS_U   + (size_t)1024*NI*2;         // 1024*1408 bf16
static constexpr size_t WS_PAIR = WS_HBF + (size_t)1024*NI*2;         // 1024*2048 bf16
static constexpr size_t WS_SHG  = WS_PAIR+ (size_t)1024*NH*2;         // 512*5632 bf16
static constexpr size_t WS_SHU  = WS_SHG + (size_t)NT*NIS*2;
static constexpr size_t WS_SHBF = WS_SHU + (size_t)NT*NIS*2;
static constexpr size_t WS_SHP  = WS_SHBF+ (size_t)NT*NIS*2;          // 4*512*2048 bf16

// ---------------- router: one wave per token ----------------
__global__ void router_kernel(const float* __restrict__ x, const float* __restrict__ gw,
                              float* __restrict__ out_logits,
                              int* __restrict__ sel, float* __restrict__ wts)
{
    int w    = threadIdx.x >> 6;
    int lane = threadIdx.x & 63;
    int t    = blockIdx.x * 4 + w;
    int e    = lane & 7, c = lane >> 3;
    const float* xr = x  + (size_t)t * NH + c * 256;
    const float* gr = gw + (size_t)e * NH + c * 256;
    float acc = 0.f;
    #pragma unroll 8
    for (int it = 0; it < 64; ++it) {
        float4 xv = *(const float4*)(xr + it*4);
        float4 gv = *(const float4*)(gr + it*4);
        acc += xv.x*gv.x + xv.y*gv.y + xv.z*gv.z + xv.w*gv.w;
    }
    acc += __shfl_xor(acc, 8);
    acc += __shfl_xor(acc, 16);
    acc += __shfl_xor(acc, 32);
    if (lane < 8) out_logits[(size_t)t * NE + e] = acc;

    float l[8];
    #pragma unroll
    for (int j = 0; j < 8; ++j) l[j] = __shfl(acc, j);
    if (lane == 0) {
        int i1 = 0;
        #pragma unroll
        for (int j = 1; j < 8; ++j) if (l[j] > l[i1]) i1 = j;
        int i2 = -1;
        #pragma unroll
        for (int j = 0; j < 8; ++j) {
            if (j == i1) continue;
            if (i2 < 0 || l[j] > l[i2]) i2 = j;
        }
        float d  = expf(l[i2] - l[i1]);
        float w1 = 1.f / (1.f + d);
        float w2 = 1.f - w1;
        sel[2*t]   = i1;  sel[2*t+1] = i2;
        wts[2*t]   = w1;  wts[2*t+1] = w2;
    }
}

// ---------------- wave-parallel deterministic bucketing ----------------
__global__ void bucket_kernel(const int* __restrict__ sel, const float* __restrict__ wts,
                              int* __restrict__ cnt, int* __restrict__ offe,
                              int* __restrict__ tok, float* __restrict__ pwt,
                              int* __restrict__ slot)
{
    int tid  = threadIdx.x;          // 0..511
    int wid  = tid >> 6;             // expert id
    int lane = tid & 63;
    __shared__ int scnt[8], soff[8];

    unsigned long long masks[16];
    int total = 0;
    #pragma unroll
    for (int c = 0; c < 16; ++c) {
        int idx = c * 64 + lane;
        int s = sel[idx];
        unsigned long long m = __ballot(s == wid);
        masks[c] = m;
        total += __popcll(m);
    }
    if (lane == 0) { scnt[wid] = total; cnt[wid] = total; }
    __syncthreads();
    if (tid == 0) {
        int s = 0;
        #pragma unroll
        for (int j = 0; j < 8; ++j) { soff[j] = s; offe[j] = s; s += scnt[j]; }
    }
    __syncthreads();
    int pfx = soff[wid];
    unsigned long long below = (lane == 63) ? ~0ull >> 1 : ((1ull << lane) - 1);
    #pragma unroll
    for (int c = 0; c < 16; ++c) {
        int idx = c * 64 + lane;
        unsigned long long m = masks[c];
        if ((m >> lane) & 1ull) {
            int rank = pfx + (int)__popcll(m & below);
            tok[rank]  = idx >> 1;
            pwt[rank]  = wts[idx];
            slot[idx]  = rank;
        }
        pfx += (int)__popcll(m);
    }
}

// ---------------- fp32 -> bf16 cast (activations) ----------------
__global__ void cast_kernel(const float* __restrict__ src, __bf16* __restrict__ dst, long long n)
{
    long long i = ((long long)blockIdx.x * blockDim.x + threadIdx.x) * 4;
    if (i >= n) return;
    float4 v = *(const float4*)(src + i);
    __bf16 o[4] = { (__bf16)v.x, (__bf16)v.y, (__bf16)v.z, (__bf16)v.w };
    *(uint2*)(dst + i) = *(const uint2*)o;
}

// ---------------- fused silu(g)*u (bf16 in/out) ----------------
__global__ void silu_fused_kernel(const __bf16* __restrict__ g1, const __bf16* __restrict__ u1,
                                  __bf16* __restrict__ h1, long long n1,
                                  const __bf16* __restrict__ g2, const __bf16* __restrict__ u2,
                                  __bf16* __restrict__ h2, long long n2)
{
    long long i = ((long long)blockIdx.x * blockDim.x + threadIdx.x) * 8;
    const __bf16 *g, *u; __bf16* h; long long idx;
    if (i < n1)           { g = g1; u = u1; h = h1; idx = i; }
    else if (i < n1 + n2) { g = g2; u = u2; h = h2; idx = i - n1; }
    else return;
    uint4 gv = *(const uint4*)(g + idx);
    uint4 uv = *(const uint4*)(u + idx);
    const __bf16* gp = (const __bf16*)&gv;
    const __bf16* up = (const __bf16*)&uv;
    __bf16 o[8];
    #pragma unroll
    for (int j = 0; j < 8; ++j) {
        float x = (float)gp[j];
        float y = x / (1.f + __expf(-x)) * (float)up[j];
        o[j] = (__bf16)y;
    }
    *(uint4*)(h + idx) = *(const uint4*)o;
}

// ============ core 128x128 MFMA GEMM — fp32 B converted in-kernel ==========
// C[base+r, n0..] = sum_k A[row(r), k] * bf16(B[k, n0+n]).
// A bf16 [*, lda] K-contiguous (DMA-staged, XOR source swizzle).
// B fp32 [K, N] row-major (DMA-staged raw, converted in LDS to bf16 [n][k]).
// LDS: A[2][8192] @0 | Ffp32[2][16384] @16384 | Bbf[8192] @49152 = 56KB.
template<int NK, bool GATHER>
__device__ __forceinline__ void gemm_core(char* __restrict__ smem,
    const __bf16* __restrict__ A, int lda,
    const float* __restrict__ B, int ldb,
    __bf16* __restrict__ C, int ldc,
    int rows, int base, const int* __restrict__ tok, int m0, int n0)
{
    const int tid  = threadIdx.x;
    const int lane = tid & 63;
    const int wid  = tid >> 6;           // 4 waves, 2x2 grid of 64x64
    const int wr   = wid >> 1, wc = wid & 1;

    // ---- A staging (bf16 DMA): wave covers rows [wid*32, +32) in 2 instrs
    const int rs0 = (wid*2 + 0)*16 + (lane >> 2);
    const int rs1 = (wid*2 + 1)*16 + (lane >> 2);
    const int cch = lane & 3;
    int ga0 = m0 + rs0, ga1 = m0 + rs1;
    int ar0, ar1;
    if (GATHER) {
        ar0 = tok[base + (ga0 < rows ? ga0 : 0)];
        ar1 = tok[base + (ga1 < rows ? ga1 : 0)];
    } else {
        ar0 = base + (ga0 < rows ? ga0 : 0);
        ar1 = base + (ga1 < rows ? ga1 : 0);
    }
    const __bf16* a0p = A + (size_t)ar0 * lda + (cch ^ (rs0 & 3)) * 8;
    const __bf16* a1p = A + (size_t)ar1 * lda + (cch ^ (rs1 & 3)) * 8;
    char* lA0 = smem + (wid*2 + 0) * 1024;
    char* lA1 = smem + (wid*2 + 1) * 1024;

    // ---- B staging (fp32 raw DMA): wave covers k-rows [wid*8, +8) in 4 instrs
    // lane l -> k-row +(l>>5), col (l&31)*4 fp32 (16B)
    const float* bp = B + (size_t)(wid*8 + (lane >> 5)) * ldb + n0 + (lane & 31)*4;
    char* lF = smem + 16384 + wid * 4096;   // + b*16384; instr i at +i*1024

#define STAGE(b, t)                                                  \
    {                                                                \
        GLDS(a0p + (size_t)(t)*32, lA0 + (b)*8192);                  \
        GLDS(a1p + (size_t)(t)*32, lA1 + (b)*8192);                  \
        const float* bt = bp + (size_t)(t)*32*ldb;                   \
        char* fb = lF + (b)*16384;                                   \
        GLDS(bt,             fb);                                    \
        GLDS(bt + 2*ldb,     fb + 1024);                             \
        GLDS(bt + 4*ldb,     fb + 2048);                             \
        GLDS(bt + 6*ldb,     fb + 3072);                             \
    }

    // ---- convert map: thread -> B col cn, k-half ckh (chunks ckh*2, ckh*2+1)
    const int cn  = tid & 127;
    const int ckh = tid >> 7;
    const int csw = (cn >> 1) & 3;               // bf16 chunk XOR swizzle
    __bf16* bbuf = (__bf16*)(smem + 49152);
    char* bw0 = (char*)bbuf + cn*64 + (((ckh*2 + 0) ^ csw) * 16);
    char* bw1 = (char*)bbuf + cn*64 + (((ckh*2 + 1) ^ csw) * 16);

    // ---- fragment read offsets (bytes)
    const int fr = lane & 15, fq = lane >> 4;
    const int aoff = (wr*64 + fr)*64 + ((fq ^ (fr & 3)) * 16);
    const int boff = (wc*64 + fr)*64 + ((fq ^ ((fr >> 1) & 3)) * 16);

    f32x4 acc[4][4];
    #pragma unroll
    for (int i = 0; i < 4; ++i)
        #pragma unroll
        for (int j = 0; j < 4; ++j) acc[i][j] = f32x4{0.f,0.f,0.f,0.f};

    STAGE(0, 0);

    #pragma unroll 1
    for (int t = 0; t < NK; ++t) {
        if (t + 1 < NK) {
            STAGE((t + 1) & 1, t + 1);
            asm volatile("s_waitcnt vmcnt(6)" ::: "memory");   // tile t's 6 DMAs done
        } else {
            asm volatile("s_waitcnt vmcnt(0)" ::: "memory");
        }
        __builtin_amdgcn_s_barrier();

        // ---- convert tile t: Ffp32[t&1] -> Bbf (bf16 [n][k], swizzled)
        {
            const float* fp = (const float*)(smem + 16384 + (t & 1)*16384) + ckh*16*128 + cn;
            __bf16 ob[16];
            #pragma unroll
            for (int j = 0; j < 16; ++j) ob[j] = (__bf16)fp[j * 128];
            *(uint4*)bw0 = ((const uint4*)ob)[0];
            *(uint4*)bw1 = ((const uint4*)ob)[1];
        }
        asm volatile("s_waitcnt lgkmcnt(0)" ::: "memory");
        __builtin_amdgcn_s_barrier();

        // ---- MFMA tile t
        {
            const char* Ab = smem + (t & 1) * 8192;
            bf16x8 af[4], bfr[4];
            #pragma unroll
            for (int m = 0; m < 4; ++m) af[m]  = *(const bf16x8*)(Ab + aoff + m*1024);
            #pragma unroll
            for (int n = 0; n < 4; ++n) bfr[n] = *(const bf16x8*)((const char*)bbuf + boff + n*1024);
            __builtin_amdgcn_s_setprio(1);
            #pragma unroll
            for (int m = 0; m < 4; ++m)
                #pragma unroll
                for (int n = 0; n < 4; ++n)
                    acc[m][n] = __builtin_amdgcn_mfma_f32_16x16x32_bf16(af[m], bfr[n], acc[m][n], 0, 0, 0);
            __builtin_amdgcn_s_setprio(0);
        }
        asm volatile("s_waitcnt lgkmcnt(0)" ::: "memory");
        __builtin_amdgcn_s_barrier();
    }
#undef STAGE

    // ---- epilogue: per-wave LDS transpose (bf16), coalesced 16B row stores
    __bf16* ep = (__bf16*)(smem + wid * 9216);   // 64 rows x 72 bf16
    #pragma unroll
    for (int m = 0; m < 4; ++m)
        #pragma unroll
        for (int n = 0; n < 4; ++n)
            #pragma unroll
            for (int q = 0; q < 4; ++q)
                ep[(m*16 + fq*4 + q)*72 + n*16 + fr] = (__bf16)acc[m][n][q];

    const int grow = m0 + wr*64 + lane;
    if (grow < rows) {
        __bf16* cp = C + (size_t)(base + grow) * ldc + n0 + wc*64;
        const __bf16* rp = ep + lane * 72;
        #pragma unroll
        for (int j = 0; j < 8; ++j)
            *(uint4*)(cp + j*8) = *(const uint4*)(rp + j*8);
    }
}

// ---------------- phase 1: expert gate/up + shared gate/up (one dispatch) ----
__launch_bounds__(256, 2)
__global__ void gemm_p1(const __bf16* __restrict__ xbf,
                        const float* __restrict__ w_gate, const float* __restrict__ w_up,
                        const float* __restrict__ sh_gate, const float* __restrict__ sh_up,
                        __bf16* __restrict__ gbuf, __bf16* __restrict__ ubuf,
                        __bf16* __restrict__ shg, __bf16* __restrict__ shu,
                        const int* __restrict__ cnt, const int* __restrict__ offe,
                        const int* __restrict__ tok)
{
    __shared__ alignas(16) char smem[57344];
    int z = blockIdx.z;
    if (z < 16) {
        if (blockIdx.x >= NI/128) return;       // 11 n-tiles
        int e = z & 7;
        int rows = cnt[e], base = offe[e];
        int m0 = blockIdx.y * 128; if (m0 >= rows) return;
        const float* B = (z < 8 ? w_gate : w_up) + (size_t)e * NH * NI;
        __bf16* C = (z < 8 ? gbuf : ubuf);
        gemm_core<NH/32, true>(smem, xbf, NH, B, NI, C, NI,
                               rows, base, tok, m0, blockIdx.x * 128);
    } else {
        const float* B = (z == 16 ? sh_gate : sh_up);
        __bf16* C = (z == 16 ? shg : shu);
        gemm_core<NH/32, false>(smem, xbf, NH, B, NIS, C, NIS,
                                NT, 0, nullptr, blockIdx.y * 128, blockIdx.x * 128);
    }
}

// ---------------- phase 3: expert down + shared down (split-K x4) ----------
__launch_bounds__(256, 2)
__global__ void gemm_p3(const __bf16* __restrict__ hbf, const __bf16* __restrict__ shbf,
                        const float* __restrict__ w_down, const float* __restrict__ sh_down,
                        __bf16* __restrict__ pair, __bf16* __restrict__ shp,
                        const int* __restrict__ cnt, const int* __restrict__ offe)
{
    __shared__ alignas(16) char smem[57344];
    int z = blockIdx.z;
    if (z < 8) {
        int rows = cnt[z], base = offe[z];
        int m0 = blockIdx.y * 128; if (m0 >= rows) return;
        gemm_core<NI/32, false>(smem, hbf, NI, w_down + (size_t)z * NI * NH, NH,
                                pair, NH, rows, base, nullptr, m0, blockIdx.x * 128);
    } else {
        int q = z - 8;                           // K-quarter
        gemm_core<NI/32, false>(smem, shbf + q * NI, NIS,
                                sh_down + (size_t)q * NI * NH, NH,
                                shp + (size_t)q * NT * NH, NH,
                                NT, 0, nullptr, blockIdx.y * 128, blockIdx.x * 128);
    }
}

// ---------------- final combine ----------------
__global__ void combine_kernel(const float* __restrict__ x, const float* __restrict__ shexp_w,
                               const __bf16* __restrict__ shp, const __bf16* __restrict__ pair_out,
                               const int* __restrict__ slot, const float* __restrict__ wts,
                               float* __restrict__ out)
{
    int t = blockIdx.x;
    int tid = threadIdx.x;
    const float* xr = x + (size_t)t * NH;

    float p = 0.f;
    #pragma unroll
    for (int j = 0; j < 8; ++j) {
        int k = tid * 8 + j;
        p += xr[k] * shexp_w[k];
    }
    __shared__ float red[256];
    red[tid] = p;
    __syncthreads();
    for (int s = 128; s > 0; s >>= 1) {
        if (tid < s) red[tid] += red[tid + s];
        __syncthreads();
    }
    float sig = 1.f / (1.f + expf(-red[0]));

    int   s0 = slot[2*t],   s1 = slot[2*t+1];
    float w0 = wts[2*t],    w1 = wts[2*t+1];
    const __bf16* pr0 = pair_out + (size_t)s0 * NH;
    const __bf16* pr1 = pair_out + (size_t)s1 * NH;
    const __bf16* sd  = shp + (size_t)t * NH;
    float* orow = out + (size_t)t * NH;
    const size_t PS = (size_t)NT * NH;
    for (int n = tid; n < NH; n += 256) {
        float sdv = (float)sd[n] + (float)sd[n + PS] + (float)sd[n + 2*PS] + (float)sd[n + 3*PS];
        orow[n] = sdv * sig + w0 * (float)pr0[n] + w1 * (float)pr1[n];
    }
}

// ---------------- launch ----------------
extern "C" void kernel_launch(void* const* d_in, const int* in_sizes, int n_in,
                              void* d_out, int out_size, void* d_ws, size_t ws_size,
                              hipStream_t stream)
{
    const float* x       = (const float*)d_in[0];
    const float* gate_w  = (const float*)d_in[1];
    const float* w_gate  = (const float*)d_in[2];
    const float* w_up    = (const float*)d_in[3];
    const float* w_down  = (const float*)d_in[4];
    const float* sh_gate = (const float*)d_in[5];
    const float* sh_up   = (const float*)d_in[6];
    const float* sh_down = (const float*)d_in[7];
    const float* shexp_g = (const float*)d_in[8];

    float* out        = (float*)d_out;
    float* out_logits = out + (size_t)NT * NH;

    char* ws = (char*)d_ws;
    __bf16* xbf  = (__bf16*)(ws + WS_XBF);
    int*    sel  = (int*)  (ws + WS_SEL);
    float*  wts  = (float*)(ws + WS_WTS);
    int*    cnt  = (int*)  (ws + WS_CNT);
    int*    offe = (int*)  (ws + WS_OFFE);
    int*    tok  = (int*)  (ws + WS_TOK);
    float*  pwt  = (float*)(ws + WS_PWT);
    int*    slot = (int*)  (ws + WS_SLOT);
    __bf16* gbuf = (__bf16*)(ws + WS_G);
    __bf16* ubuf = (__bf16*)(ws + WS_U);
    __bf16* hbf  = (__bf16*)(ws + WS_HBF);
    __bf16* pair = (__bf16*)(ws + WS_PAIR);
    __bf16* shg  = (__bf16*)(ws + WS_SHG);
    __bf16* shu  = (__bf16*)(ws + WS_SHU);
    __bf16* shbf = (__bf16*)(ws + WS_SHBF);
    __bf16* shp  = (__bf16*)(ws + WS_SHP);
    (void)pwt; (void)in_sizes; (void)n_in; (void)out_size; (void)ws_size;

    router_kernel<<<dim3(128), dim3(256), 0, stream>>>(x, gate_w, out_logits, sel, wts);
    bucket_kernel<<<dim3(1), dim3(512), 0, stream>>>(sel, wts, cnt, offe, tok, pwt, slot);
    cast_kernel<<<dim3(1024), dim3(256), 0, stream>>>(x, xbf, (long long)NT * NH);

    // phase 1: gate experts (z=0..7), up experts (8..15), shared gate (16), shared up (17)
    gemm_p1<<<dim3(44, 4, 18), dim3(256), 0, stream>>>(
        xbf, w_gate, w_up, sh_gate, sh_up, gbuf, ubuf, shg, shu, cnt, offe, tok);

    // silu
    silu_fused_kernel<<<dim3(2112), dim3(256), 0, stream>>>(
        gbuf, ubuf, hbf, (long long)1024 * NI,
        shg, shu, shbf, (long long)NT * NIS);

    // phase 3: expert down (z=0..7), shared down split-K x4 (z=8..11)
    gemm_p3<<<dim3(16, 4, 12), dim3(256), 0, stream>>>(
        hbf, shbf, w_down, sh_down, pair, shp, cnt, offe);

    combine_kernel<<<dim3(NT), dim3(256), 0, stream>>>(
        x, shexp_g, shp, pair, slot, wts, out);
}